// Round 5
// baseline (286.783 us; speedup 1.0000x reference)
//
#include <hip/hip_runtime.h>

#define POOL 7
#define NROIS 1000
#define NCELLS (NROIS * POOL * POOL)     // 49000 output cells
#define IMG_W 128
#define NCH 1024
#define NXCD 8
#define CG_CH 128                        // channels per XCD slice (512 B)
#define CELLS_PER_BLK 8                  // 256 thr = 8 cells x 32 lanes x f4
#define NBLK_PER_XCD (NCELLS / CELLS_PER_BLK)   // 6125

typedef float f4 __attribute__((ext_vector_type(4)));

// Pass 1: counting-sort the 1000 ROIs by y (y in [0,64)) into workspace.
// sorted[rank] = roi record, perm[rank] = original roi index.
// Purpose: the main kernel processes ROIs in rank order, so concurrently
// resident ROIs on an XCD share a narrow y-band of its 8 MB channel slice
// -> cross-ROI corner-row re-reads hit the 4 MB L2 instead of thrashing.
__global__ __launch_bounds__(256) void roi_sort_kernel(
    const int* __restrict__ rois, int4* __restrict__ sorted,
    int* __restrict__ perm)
{
    __shared__ int hist[64];
    __shared__ int base[64];
    const int t = threadIdx.x;
    if (t < 64) hist[t] = 0;
    __syncthreads();
    for (int i = t; i < NROIS; i += 256)
        atomicAdd(&hist[rois[4 * i + 1] & 63], 1);
    __syncthreads();
    if (t == 0) {
        int acc = 0;
        for (int b = 0; b < 64; ++b) { base[b] = acc; acc += hist[b]; }
    }
    __syncthreads();
    for (int i = t; i < NROIS; i += 256) {
        const int4 r = ((const int4*)rois)[i];
        const int pos = atomicAdd(&base[r.y & 63], 1);
        sorted[pos] = r;
        perm[pos] = i;
    }
}

// Pass 2: channel-sharded ROI bilinear pooling, G=8 (128-ch slice per XCD),
// cells walked in y-sorted ROI order. bid%8 == XCD id (round-robin dispatch
// heuristic). Each XCD reads only its exclusive 8 MB channel slice; sorted
// order keeps the instantaneous working set to a y-band that fits L2.
__global__ __launch_bounds__(256) void roi_pool_kernel(
    const float* __restrict__ img,
    const int4* __restrict__ sorted,
    const int* __restrict__ perm,
    float* __restrict__ out)
{
    const unsigned bid  = blockIdx.x;
    const unsigned xcd  = bid & 7u;            // presumed XCD of this block
    const unsigned cblk = bid >> 3;            // 0..6124 cell-block in XCD
    const unsigned t    = threadIdx.x;         // 0..255
    const unsigned sc   = cblk * CELLS_PER_BLK + (t >> 5);  // sorted cell idx
    const unsigned lane = t & 31u;

    const unsigned rank = sc / 49u;            // sorted ROI rank
    const unsigned c49  = sc - rank * 49u;
    const unsigned py   = c49 / 7u;
    const unsigned px   = c49 - py * 7u;

    const int4 r   = sorted[rank];             // x, y, w, h (sorted record)
    const int orig = perm[rank];               // original ROI index (output)
    const int x = r.x, y = r.y, w = r.z, h = r.w;

    // y-axis source coords (match reference op order exactly)
    const float hf = (float)h;
    float fy = ((float)py + 0.5f) * (hf / (float)POOL) - 0.5f;
    fy = fminf(fmaxf(fy, 0.0f), fmaxf(hf - 1.0f, 0.0f));
    const int   iy0 = (int)floorf(fy);
    const int   iy1 = min(iy0 + 1, h - 1);
    const float wy  = fy - (float)iy0;
    const int   y0  = y + iy0;
    const int   y1  = y + iy1;

    // x-axis source coords
    const float wf = (float)w;
    float fx = ((float)px + 0.5f) * (wf / (float)POOL) - 0.5f;
    fx = fminf(fmaxf(fx, 0.0f), fmaxf(wf - 1.0f, 0.0f));
    const int   ix0 = (int)floorf(fx);
    const int   ix1 = min(ix0 + 1, w - 1);
    const float wx  = fx - (float)ix0;
    const int   x0  = x + ix0;
    const int   x1  = x + ix1;

    // channel offset: this XCD's slice base + lane quad
    const unsigned choff = xcd * CG_CH + lane * 4u;

    const f4* p00 = (const f4*)(img + ((size_t)y0 * IMG_W + x0) * NCH + choff);
    const f4* p01 = (const f4*)(img + ((size_t)y0 * IMG_W + x1) * NCH + choff);
    const f4* p10 = (const f4*)(img + ((size_t)y1 * IMG_W + x0) * NCH + choff);
    const f4* p11 = (const f4*)(img + ((size_t)y1 * IMG_W + x1) * NCH + choff);

    const unsigned cell = (unsigned)orig * 49u + c49;   // original output slot
    f4* po = (f4*)(out + (size_t)cell * NCH + choff);

    const f4 a = *p00;
    const f4 b = *p01;
    const f4 c = *p10;
    const f4 d = *p11;

    const float owx = 1.0f - wx;
    const float owy = 1.0f - wy;

    const f4 top = a * owx + b * wx;
    const f4 bot = c * owx + d * wx;
    const f4 res = top * owy + bot * wy;

    __builtin_nontemporal_store(res, po);
}

extern "C" void kernel_launch(void* const* d_in, const int* in_sizes, int n_in,
                              void* d_out, int out_size, void* d_ws, size_t ws_size,
                              hipStream_t stream)
{
    const float* img  = (const float*)d_in[0];
    const int*   rois = (const int*)d_in[1];
    float*       out  = (float*)d_out;

    int4* sorted = (int4*)d_ws;                       // 1000 * 16 B
    int*  perm   = (int*)((char*)d_ws + NROIS * 16);  // 1000 * 4 B

    roi_sort_kernel<<<1, 256, 0, stream>>>(rois, sorted, perm);

    const int nblocks = NBLK_PER_XCD * NXCD;          // 49000
    roi_pool_kernel<<<nblocks, 256, 0, stream>>>(img, sorted, perm, out);
}